// Round 6
// baseline (116.332 us; speedup 1.0000x reference)
//
#include <hip/hip_runtime.h>

#define NN 4096
#define NC 10
#define NW 64            // u64 words per adjacency row
#define CHW 16           // words per staged chunk
#define NCHUNK 4         // NW / CHW
typedef unsigned long long u64;

#define S1F 0.73105857863000489f   // sigmoid(1.0)

// ---------------- kernel 1: pack adjacency rows into bitmasks + degrees ----
__global__ __launch_bounds__(256) void pack_bits_kernel(
    const int* __restrict__ adj, u64* __restrict__ bits, int* __restrict__ deg) {
  int p = blockIdx.x;
  int tid = threadIdx.x;
  int wv = tid >> 6, lane = tid & 63;
  const int* row = adj + (size_t)p * NN;
  int cnt = 0;
  for (int w = wv; w < NW; w += 4) {
    int a = row[(w << 6) + lane];
    u64 b = __ballot(a != 0);
    if (lane == 0) bits[(size_t)p * NW + w] = b;
    cnt += (a != 0) ? 1 : 0;
  }
  __shared__ int red[256];
  red[tid] = cnt;
  __syncthreads();
  for (int s = 128; s > 0; s >>= 1) {
    if (tid < s) red[tid] += red[tid + s];
    __syncthreads();
  }
  if (tid == 0) deg[p] = red[0];
}

// ---------------- kernel 2: per-node CE + pos + per-class masked counts ----
__global__ __launch_bounds__(256) void node_kernel(
    const float* __restrict__ preds, const int* __restrict__ labels,
    const int* __restrict__ mask, float* __restrict__ pos,
    int* __restrict__ Ncnt, float* __restrict__ ceAcc) {
  int n = blockIdx.x * blockDim.x + threadIdx.x;
  float ce = 0.f;
  if (n < NN) {
    int l = labels[n];
    float r[NC];
    float mx = -1e30f, rl = 0.f;
#pragma unroll
    for (int c = 0; c < NC; c++) {
      float v = preds[n * NC + c];
      r[c] = v;
      if (c == l) rl = v;
      mx = fmaxf(mx, v);
    }
    float s = 0.f;
#pragma unroll
    for (int c = 0; c < NC; c++) s += expf(r[c] - mx);
    float lse = mx + logf(s);
    pos[n] = rl;
    ce = lse - rl;
    if (mask[n] != 0) atomicAdd(&Ncnt[l], 1);
  }
  __shared__ float red[256];
  red[threadIdx.x] = ce;
  __syncthreads();
  for (int s = 128; s > 0; s >>= 1) {
    if (threadIdx.x < s) red[threadIdx.x] += red[threadIdx.x + s];
    __syncthreads();
  }
  if (threadIdx.x == 0) atomicAdd(ceAcc, red[0]);
}

// ---------------- kernel 3: deterministic mask compaction (1 block) --------
__global__ __launch_bounds__(256) void compact_kernel(
    const int* __restrict__ mask, int* __restrict__ list, int* __restrict__ Mcount) {
  __shared__ int cnt[256];
  int tid = threadIdx.x;
  int base = tid * 16;
  int c = 0;
  for (int i = 0; i < 16; i++) c += (mask[base + i] != 0) ? 1 : 0;
  cnt[tid] = c;
  __syncthreads();
  for (int s = 1; s < 256; s <<= 1) {
    int v = (tid >= s) ? cnt[tid - s] : 0;
    __syncthreads();
    cnt[tid] += v;
    __syncthreads();
  }
  int off = cnt[tid] - c;
  for (int i = 0; i < 16; i++) {
    int idx = base + i;
    if (mask[idx] != 0) list[off++] = idx;
  }
  if (tid == 255) *Mcount = cnt[255];
}

// ---------------- kernel 4: wave-autonomous 32x32 pair tiles ---------------
// 512 blocks x 4 waves = 2048 waves ~= ntiles(M=2048): every wave owns ~1
// tile, uniform 2 blocks/CU. No __syncthreads in the main loop (per-wave LDS
// slice, wave-order DS + lgkmcnt). All epilogue scattered data (adjacency
// words + preds) is register-prefetched so its L2 latency hides under the
// ~8K-cycle popcount loop.
__global__ __launch_bounds__(256, 2) void pair_kernel(
    const u64* __restrict__ bits, const int* __restrict__ deg,
    const float* __restrict__ pos, const float* __restrict__ preds,
    const int* __restrict__ labels, const int* __restrict__ list,
    const int* __restrict__ Mcount,
    float* __restrict__ gT, int* __restrict__ gS, int* __restrict__ gI) {
  __shared__ __align__(16) u64 TB[4][64][CHW];   // 32 KB: 4 waves x 64 rows x 16 words
  __shared__ int mNode[4][64], mLab[4][64], mDeg[4][64], mSelf[4][64];
  __shared__ float mPos[4][64];
  __shared__ float binT[100];
  __shared__ int fS[100], fI[100];

  int tid = threadIdx.x;
  int wv = tid >> 6, lane = tid & 63;
  for (int b = tid; b < 100; b += 256) { binT[b] = 0.f; fS[b] = 0; fI[b] = 0; }
  __syncthreads();                                // bins ready (barrier #1)

  int M = *Mcount;
  int ntp = (M + 31) >> 5;
  int ntiles = (ntp * (ntp + 1)) >> 1;
  int gw = blockIdx.x * 4 + wv;
  int nw = gridDim.x * 4;                         // 2048 waves

  int lp = lane >> 3, lq = lane & 7;              // 8x8 lane grid, 4x4 pairs each
  int rowHash = (lane >> 2) & 7;                  // staging swizzle for row=lane
  u64 (*tb)[CHW] = TB[wv];

  for (int t = gw; t < ntiles; t += nw) {
    int tp = 0, rem = t;
    while (rem >= ntp - tp) { rem -= ntp - tp; tp++; }
    int tq = tp + rem;
    bool diag = (tp == tq);

    // ---- per-row metadata (lane owns row `lane`: 0-31 = P, 32-63 = Q)
    int mi = (lane < 32) ? (tp * 32 + lane) : (tq * 32 + (lane - 32));
    int nd = (mi < M) ? list[mi] : -1;
    int lb = -1, dg = 0, sf = 0;
    float ps = 0.f;
    if (nd >= 0) {
      lb = labels[nd];
      dg = deg[nd];
      ps = pos[nd];
      sf = (int)((bits[(size_t)nd * NW + (nd >> 6)] >> (nd & 63)) & 1ULL);
    }
    mNode[wv][lane] = nd; mLab[wv][lane] = lb; mDeg[wv][lane] = dg;
    mSelf[wv][lane] = sf; mPos[wv][lane] = ps;
    asm volatile("s_waitcnt lgkmcnt(0)" ::: "memory");  // meta visible wave-wide

    // ---- gather my 4 P rows + 4 Q rows metadata into registers
    int pgs[4], lis[4], dgp[4], sfp[4];
    float pps[4];
#pragma unroll
    for (int i = 0; i < 4; i++) {
      int r = (lp << 2) + i;
      pgs[i] = mNode[wv][r]; lis[i] = mLab[wv][r]; dgp[i] = mDeg[wv][r];
      sfp[i] = mSelf[wv][r]; pps[i] = mPos[wv][r];
    }
    int qgs[4], ljs[4], dgq[4], sfq[4];
    float pqs[4];
#pragma unroll
    for (int j = 0; j < 4; j++) {
      int r = 32 + (lq << 2) + j;
      qgs[j] = mNode[wv][r]; ljs[j] = mLab[wv][r]; dgq[j] = mDeg[wv][r];
      sfq[j] = mSelf[wv][r]; pqs[j] = mPos[wv][r];
    }

    const u64* rowp = bits + (size_t)((nd >= 0) ? nd : 0) * NW;
    bool live = (nd >= 0);

    // ---- issue chunk-0 staging loads first (needed soonest)
    ulonglong2 pf[8];
#pragma unroll
    for (int x = 0; x < 8; x++)
      pf[x] = live ? *(const ulonglong2*)(rowp + (x << 1))
                   : make_ulonglong2(0ULL, 0ULL);

    // ---- prefetch per-pair adjacency words (epilogue data, L2-resident)
    u64 rwp[4][4], rwq[4][4];
#pragma unroll
    for (int i = 0; i < 4; i++)
#pragma unroll
      for (int j = 0; j < 4; j++) {
        int pg = (pgs[i] >= 0) ? pgs[i] : 0;
        int qg = (qgs[j] >= 0) ? qgs[j] : 0;
        rwp[i][j] = bits[(size_t)pg * NW + (qg >> 6)];
        rwq[i][j] = bits[(size_t)qg * NW + (pg >> 6)];
      }

    int acc[4][4];
#pragma unroll
    for (int i = 0; i < 4; i++)
#pragma unroll
      for (int j = 0; j < 4; j++) acc[i][j] = 0;

    float efv[4][4], erv[4][4];

    for (int c = 0; c < NCHUNK; c++) {
      // write staged regs to this wave's LDS slice (swizzled 16B slots)
#pragma unroll
      for (int x = 0; x < 8; x++)
        *(ulonglong2*)&tb[lane][(x ^ rowHash) << 1] = pf[x];
      // issue next chunk's global loads (in flight under compute)
      if (c < NCHUNK - 1) {
        const u64* src = rowp + ((c + 1) * CHW);
#pragma unroll
        for (int x = 0; x < 8; x++)
          pf[x] = live ? *(const ulonglong2*)(src + (x << 1))
                       : make_ulonglong2(0ULL, 0ULL);
      } else {
        // last chunk: issue epilogue pred loads (hidden under final popc)
#pragma unroll
        for (int i = 0; i < 4; i++)
#pragma unroll
          for (int j = 0; j < 4; j++) {
            int pg = (pgs[i] >= 0) ? pgs[i] : 0;
            int qg = (qgs[j] >= 0) ? qgs[j] : 0;
            efv[i][j] = preds[qg * NC + ((lis[i] >= 0) ? lis[i] : 0)];
            erv[i][j] = preds[pg * NC + ((ljs[j] >= 0) ? ljs[j] : 0)];
          }
      }
      // wave-synchronous: drain DS writes before reads (no barrier)
      asm volatile("s_waitcnt lgkmcnt(0)" ::: "memory");

#pragma unroll
      for (int y = 0; y < 8; y++) {               // 8 word-pairs per chunk
        ulonglong2 RP[4], RQ[4];
#pragma unroll
        for (int i = 0; i < 4; i++)
          RP[i] = *(ulonglong2*)&tb[(lp << 2) + i][(y ^ lp) << 1];
#pragma unroll
        for (int j = 0; j < 4; j++)
          RQ[j] = *(ulonglong2*)&tb[32 + (lq << 2) + j][(y ^ lq) << 1];
#pragma unroll
        for (int i = 0; i < 4; i++)
#pragma unroll
          for (int j = 0; j < 4; j++)
            acc[i][j] += (int)__popcll(RP[i].x & RQ[j].x)
                       + (int)__popcll(RP[i].y & RQ[j].y);
      }
    }

    // ---- epilogue: both orientations per unordered pair, all data in regs
#pragma unroll
    for (int i = 0; i < 4; i++) {
      if (pgs[i] < 0) continue;
      int pl = (lp << 2) + i;
      int li = lis[i];
#pragma unroll
      for (int j = 0; j < 4; j++) {
        if (qgs[j] < 0) continue;
        int lj = ljs[j];
        if (li == lj) continue;                   // only off-diag bins matter
        int qr = (lq << 2) + j;
        if (diag && pl >= qr) continue;           // unordered once on diag tiles
        int inter = acc[i][j];
        int apq = (int)((rwp[i][j] >> (qgs[j] & 63)) & 1ULL);
        int aqp = (int)((rwq[i][j] >> (pgs[i] & 63)) & 1ULL);
        int sub_f = dgp[i] - inter - (apq & (sfq[j] ^ 1));
        int sub_r = dgq[j] - inter - (aqp & (sfp[i] ^ 1));
        float rden = 1.f / (1.f + S1F * (float)inter);
        float xf = (1.f + S1F * (float)sub_f) * rden;
        float xr = (1.f + S1F * (float)sub_r) * rden;
        float Ef = __expf(efv[i][j] - pps[i]);
        float Er = __expf(erv[i][j] - pqs[j]);
        float vf = 1.f / (1.f + __expf(xf));      // 1 - sigmoid(x)
        float vr = 1.f / (1.f + __expf(xr));
        atomicAdd(&binT[li * NC + lj], Ef * vf);
        atomicAdd(&binT[lj * NC + li], Er * vr);
        if (sub_f > 0) fS[li * NC + lj] = 1;      // same-value stores: safe
        if (sub_r > 0) fS[lj * NC + li] = 1;
        if (inter > 0) { fI[li * NC + lj] = 1; fI[lj * NC + li] = 1; }
      }
    }
    // next tile: DS in-order per wave makes meta/TB rewrite safe, no barrier
  }

  __syncthreads();                                // all waves done (barrier #2)
  for (int b = tid; b < 100; b += 256) {
    float v = binT[b];
    if (v != 0.f) atomicAdd(&gT[b], v);
    if (fS[b]) atomicOr(&gS[b], 1);
    if (fI[b]) atomicOr(&gI[b], 1);
  }
}

// ---------------- kernel 5: final gate + reduce ----------------------------
__global__ __launch_bounds__(128) void finalize_kernel(
    const float* __restrict__ gT, const int* __restrict__ gS,
    const int* __restrict__ gI, const int* __restrict__ Ncnt,
    const float* __restrict__ ceAcc, float* __restrict__ out) {
  __shared__ float red[128];
  int tid = threadIdx.x;
  float val = 0.f;
  if (tid < 100) {
    int i = tid / NC, j = tid - (tid / NC) * NC;
    if (i != j && gS[tid] != 0 && gI[tid] != 0) {
      float Ni = fmaxf((float)Ncnt[i], 1.f);
      float Nj = fmaxf((float)Ncnt[j], 1.f);
      val = gT[tid] / (Ni * Nj);
    }
  }
  red[tid] = val;
  __syncthreads();
  for (int s = 64; s > 0; s >>= 1) {
    if (tid < s) red[tid] += red[tid + s];
    __syncthreads();
  }
  if (tid == 0) out[0] = ceAcc[0] / (float)NN + 0.001f * red[0];
}

// ---------------- launch ---------------------------------------------------
extern "C" void kernel_launch(void* const* d_in, const int* in_sizes, int n_in,
                              void* d_out, int out_size, void* d_ws, size_t ws_size,
                              hipStream_t stream) {
  const float* preds  = (const float*)d_in[0];
  const int*   labels = (const int*)d_in[1];
  const int*   mask   = (const int*)d_in[2];
  const int*   adj    = (const int*)d_in[3];

  char* ws = (char*)d_ws;
  u64*   bits  = (u64*)(ws + 0);
  int*   deg   = (int*)(ws + 2097152);
  float* pos   = (float*)(ws + 2113536);
  int*   list  = (int*)(ws + 2129920);
  char*  accb  = ws + 2146304;
  float* ceAcc = (float*)(accb + 0);
  int*   Mcnt  = (int*)(accb + 8);
  int*   Ncnt  = (int*)(accb + 16);      // 10 ints
  float* gT    = (float*)(accb + 64);    // 100 floats
  int*   gS    = (int*)(accb + 512);     // 100 ints (flags)
  int*   gI    = (int*)(accb + 1024);    // 100 ints (flags)

  hipMemsetAsync(accb, 0, 1536, stream);

  hipLaunchKernelGGL(pack_bits_kernel, dim3(NN), dim3(256), 0, stream, adj, bits, deg);
  hipLaunchKernelGGL(node_kernel, dim3(NN / 256), dim3(256), 0, stream,
                     preds, labels, mask, pos, Ncnt, ceAcc);
  hipLaunchKernelGGL(compact_kernel, dim3(1), dim3(256), 0, stream, mask, list, Mcnt);
  // 512 blocks x 4 waves = 2048 waves: ~1 tile/wave at M=2048 (2080 tiles),
  // uniform 2 blocks/CU; grid-stride covers larger M (8256 tiles @ M=4096).
  hipLaunchKernelGGL(pair_kernel, dim3(512), dim3(256), 0, stream,
                     bits, deg, pos, preds, labels, list, Mcnt, gT, gS, gI);
  hipLaunchKernelGGL(finalize_kernel, dim3(1), dim3(128), 0, stream,
                     gT, gS, gI, Ncnt, ceAcc, (float*)d_out);
}